// Round 2
// baseline (445.515 us; speedup 1.0000x reference)
//
#include <hip/hip_runtime.h>
#include <math.h>

#define B_ 2
#define S_ 1024
#define E_ 1024
#define H_ 16
#define T_ 32
#define D_ 64
#define SCALE_F 0.7071067811865476f

// ---------------------------------------------------------------------------
// A[h,t,i] = (1/sqrt(D)) * sum_j proj[h,j] * tpl_norm[h,t,(i-j) mod D]
// (collapse of irfft(rfft(q)*conj(rfft(tpl_n))) dotted with proj)
// ---------------------------------------------------------------------------
__global__ __launch_bounds__(64) void k_prep_A(const float* __restrict__ tpl,
                                               const float* __restrict__ proj,
                                               float* __restrict__ A) {
  int ht = blockIdx.x;            // h*T + t
  int h = ht >> 5;
  int lane = threadIdx.x;         // 0..63
  float tv = tpl[ht * D_ + lane];
  float ss = tv * tv;
#pragma unroll
  for (int off = 1; off < 64; off <<= 1) ss += __shfl_xor(ss, off);
  float rn = 1.0f / fmaxf(sqrtf(ss), 1e-12f);
  __shared__ float tn[D_];
  tn[lane] = tv * rn;
  __syncthreads();
  float acc = 0.f;
#pragma unroll
  for (int j = 0; j < D_; ++j) acc += proj[h * D_ + j] * tn[(lane - j) & 63];
  A[ht * D_ + lane] = acc * 0.125f;   // 1/sqrt(64)
}

// ---------------------------------------------------------------------------
// Fused QKV GEMM. Y[m,n] = sum_k X[m,k]*W[n,k], M=2048, N=1024, K=1024.
// 64x64 tile, BK=16, 256 threads, 4x4 micro-tile.
// z==2 (V): store tile to Vout.
// z<2 (Q/K): N-tile == one head (D=64). Fused epilogue: RoPE + signature
//   matvec (x A[h]) + l2norm over t, write Sig[b,h,s,t]. q/k never hit HBM.
// ---------------------------------------------------------------------------
__global__ __launch_bounds__(256) void k_gemm_qkv(const float* __restrict__ X,
                                                  const float* __restrict__ Wq,
                                                  const float* __restrict__ Wk,
                                                  const float* __restrict__ Wv,
                                                  const float* __restrict__ A,
                                                  float* __restrict__ Qs,
                                                  float* __restrict__ Ks,
                                                  float* __restrict__ Vout) {
  __shared__ float As[16][68];
  __shared__ float Bs[16][68];
  __shared__ float tile[64][68];
  __shared__ float Ash[32][64];
  __shared__ float rowbuf[4][64];

  const int K = 1024, N = 1024;
  int z = blockIdx.z;
  const float* W = (z == 0) ? Wq : (z == 1) ? Wk : Wv;
  int tid = threadIdx.x;
  int tx = tid & 15, ty = tid >> 4;
  int m0 = blockIdx.y << 6, n0 = blockIdx.x << 6;
  int h = blockIdx.x;             // head index (valid when z<2)

  if (z != 2) {
    for (int i = tid; i < 32 * 64; i += 256)
      Ash[i >> 6][i & 63] = A[h * (T_ * D_) + i];
  }

  int lr = tid >> 2, lc = (tid & 3) << 2;
  float acc[4][4] = {};
  for (int k0 = 0; k0 < K; k0 += 16) {
    float4 av = *reinterpret_cast<const float4*>(&X[(m0 + lr) * K + k0 + lc]);
    float4 bv = *reinterpret_cast<const float4*>(&W[(n0 + lr) * K + k0 + lc]);
    __syncthreads();
    As[lc + 0][lr] = av.x; As[lc + 1][lr] = av.y; As[lc + 2][lr] = av.z; As[lc + 3][lr] = av.w;
    Bs[lc + 0][lr] = bv.x; Bs[lc + 1][lr] = bv.y; Bs[lc + 2][lr] = bv.z; Bs[lc + 3][lr] = bv.w;
    __syncthreads();
#pragma unroll
    for (int kk = 0; kk < 16; ++kk) {
      float4 a4 = *reinterpret_cast<const float4*>(&As[kk][ty << 2]);
      float4 b4 = *reinterpret_cast<const float4*>(&Bs[kk][tx << 2]);
      float av_[4] = {a4.x, a4.y, a4.z, a4.w};
      float bv_[4] = {b4.x, b4.y, b4.z, b4.w};
#pragma unroll
      for (int i = 0; i < 4; ++i)
#pragma unroll
        for (int j = 0; j < 4; ++j)
          acc[i][j] = fmaf(av_[i], bv_[j], acc[i][j]);
    }
  }

  if (z == 2) {
#pragma unroll
    for (int i = 0; i < 4; ++i) {
      float4 o = make_float4(acc[i][0], acc[i][1], acc[i][2], acc[i][3]);
      *reinterpret_cast<float4*>(&Vout[(m0 + (ty << 2) + i) * N + n0 + (tx << 2)]) = o;
    }
    return;
  }

  // ---- fused RoPE + signature epilogue (all LDS traffic is wave-local) ----
  float* Sig = (z == 0) ? Qs : Ks;
#pragma unroll
  for (int i = 0; i < 4; ++i)
    *reinterpret_cast<float4*>(&tile[(ty << 2) + i][tx << 2]) =
        make_float4(acc[i][0], acc[i][1], acc[i][2], acc[i][3]);
  // tile rows (w*16..w*16+15) are written by exactly the threads of wave w,
  // and read only by wave w: same-wave LDS ops execute in order -> no barrier.
  int w = tid >> 6, lane = tid & 63;
  int p = lane >> 1;
  float inv_freq = 1.0f / powf(10000.0f, (float)(2 * p) / 64.0f);
  int t = lane & 31, half = lane >> 5;
  for (int rr = 0; rr < 16; ++rr) {
    int r = (w << 4) + rr;
    int m = m0 + r;
    int b = m >> 10, s = m & 1023;
    __builtin_amdgcn_wave_barrier();
    float v = tile[r][lane];
    float sn, c;
    sincosf((float)s * inv_freq, &sn, &c);
    float partner = __shfl_xor(v, 1);
    float vr = (lane & 1) ? (partner * sn + v * c) : (v * c - partner * sn);
    rowbuf[w][lane] = vr;
    __builtin_amdgcn_wave_barrier();
    float dot = 0.f;
#pragma unroll
    for (int i2 = 0; i2 < 32; ++i2)
      dot += rowbuf[w][half * 32 + i2] * Ash[t][half * 32 + i2];
    dot += __shfl_xor(dot, 32);   // both halves hold full dot for t
    float ss = dot * dot;
#pragma unroll
    for (int off = 1; off < 32; off <<= 1) ss += __shfl_xor(ss, off);
    float rn = 1.0f / fmaxf(sqrtf(ss), 1e-12f);
    if (lane < 32) Sig[(((b << 4) + h) * S_ + s) * T_ + t] = dot * rn;
  }
}

// ---------------------------------------------------------------------------
// Plain GEMM (final projection): Y = X @ W^T
// ---------------------------------------------------------------------------
__global__ __launch_bounds__(256) void k_gemm(const float* __restrict__ X,
                                              const float* __restrict__ W,
                                              float* __restrict__ Y) {
  __shared__ float As[16][68];
  __shared__ float Bs[16][68];
  const int K = 1024, N = 1024;
  int tid = threadIdx.x;
  int tx = tid & 15, ty = tid >> 4;
  int m0 = blockIdx.y << 6, n0 = blockIdx.x << 6;
  int lr = tid >> 2, lc = (tid & 3) << 2;
  float acc[4][4] = {};
  for (int k0 = 0; k0 < K; k0 += 16) {
    float4 av = *reinterpret_cast<const float4*>(&X[(m0 + lr) * K + k0 + lc]);
    float4 bv = *reinterpret_cast<const float4*>(&W[(n0 + lr) * K + k0 + lc]);
    __syncthreads();
    As[lc + 0][lr] = av.x; As[lc + 1][lr] = av.y; As[lc + 2][lr] = av.z; As[lc + 3][lr] = av.w;
    Bs[lc + 0][lr] = bv.x; Bs[lc + 1][lr] = bv.y; Bs[lc + 2][lr] = bv.z; Bs[lc + 3][lr] = bv.w;
    __syncthreads();
#pragma unroll
    for (int kk = 0; kk < 16; ++kk) {
      float4 a4 = *reinterpret_cast<const float4*>(&As[kk][ty << 2]);
      float4 b4 = *reinterpret_cast<const float4*>(&Bs[kk][tx << 2]);
      float av_[4] = {a4.x, a4.y, a4.z, a4.w};
      float bv_[4] = {b4.x, b4.y, b4.z, b4.w};
#pragma unroll
      for (int i = 0; i < 4; ++i)
#pragma unroll
        for (int j = 0; j < 4; ++j)
          acc[i][j] = fmaf(av_[i], bv_[j], acc[i][j]);
    }
  }
#pragma unroll
  for (int i = 0; i < 4; ++i) {
    float4 o = make_float4(acc[i][0], acc[i][1], acc[i][2], acc[i][3]);
    *reinterpret_cast<float4*>(&Y[(m0 + (ty << 2) + i) * N + n0 + (tx << 2)]) = o;
  }
}

// ---------------------------------------------------------------------------
// Attention: per (b,h), 64-query tile. scores bounded by |SCALE| -> no
// max-subtraction. out[b,q,h,d] = sum_k softmax(q_sig·k_sig*SCALE) v[k,d]
// ---------------------------------------------------------------------------
__global__ __launch_bounds__(256) void k_attention(const float* __restrict__ Qs,
                                                   const float* __restrict__ Ks,
                                                   const float* __restrict__ V,
                                                   float* __restrict__ O) {
  __shared__ float qsh[64][36];
  __shared__ float ksh[32][68];
  __shared__ float vsh[64][64];
  __shared__ float esh[64][68];

  int tid = threadIdx.x;
  int bh = blockIdx.y;
  int b = bh >> 4, h = bh & 15;
  int q0 = blockIdx.x << 6;
  const float* qsig = Qs + (size_t)(bh * S_ + q0) * T_;
  const float* ksig = Ks + (size_t)bh * S_ * T_;

  for (int i = tid; i < 512; i += 256) {
    int r = i >> 3, c = (i & 7) << 2;
    *reinterpret_cast<float4*>(&qsh[r][c]) =
        *reinterpret_cast<const float4*>(&qsig[r * 32 + c]);
  }

  int tq = tid >> 4, tk = tid & 15;
  int qi = tid >> 2, dq = tid & 3;
  float accv[16] = {};
  float den = 0.f;

  for (int kt = 0; kt < 16; ++kt) {
    int k0 = kt << 6;
    __syncthreads();
    for (int i = tid; i < 512; i += 256) {
      int r = i >> 3, c = (i & 7) << 2;
      float4 kv = *reinterpret_cast<const float4*>(&ksig[(k0 + r) * 32 + c]);
      ksh[c + 0][r] = kv.x; ksh[c + 1][r] = kv.y; ksh[c + 2][r] = kv.z; ksh[c + 3][r] = kv.w;
    }
    for (int i = tid; i < 1024; i += 256) {
      int r = i >> 4, c = (i & 15) << 2;
      *reinterpret_cast<float4*>(&vsh[r][c]) =
          *reinterpret_cast<const float4*>(&V[((size_t)(b * S_ + k0 + r) * H_ + h) * D_ + c]);
    }
    __syncthreads();

    float sc[4][4] = {};
#pragma unroll
    for (int t4 = 0; t4 < 32; t4 += 4) {
      float4 qv[4], kv[4];
#pragma unroll
      for (int i = 0; i < 4; ++i)
        qv[i] = *reinterpret_cast<const float4*>(&qsh[(tq << 2) + i][t4]);
#pragma unroll
      for (int tt = 0; tt < 4; ++tt)
        kv[tt] = *reinterpret_cast<const float4*>(&ksh[t4 + tt][tk << 2]);
#pragma unroll
      for (int i = 0; i < 4; ++i) {
        float qa[4] = {qv[i].x, qv[i].y, qv[i].z, qv[i].w};
#pragma unroll
        for (int tt = 0; tt < 4; ++tt) {
          float kb[4] = {kv[tt].x, kv[tt].y, kv[tt].z, kv[tt].w};
          sc[i][0] = fmaf(qa[tt], kb[0], sc[i][0]);
          sc[i][1] = fmaf(qa[tt], kb[1], sc[i][1]);
          sc[i][2] = fmaf(qa[tt], kb[2], sc[i][2]);
          sc[i][3] = fmaf(qa[tt], kb[3], sc[i][3]);
        }
      }
    }
#pragma unroll
    for (int i = 0; i < 4; ++i) {
      float4 ev;
      ev.x = __expf(sc[i][0] * SCALE_F);
      ev.y = __expf(sc[i][1] * SCALE_F);
      ev.z = __expf(sc[i][2] * SCALE_F);
      ev.w = __expf(sc[i][3] * SCALE_F);
      *reinterpret_cast<float4*>(&esh[(tq << 2) + i][tk << 2]) = ev;
    }
    __syncthreads();

    for (int kj = 0; kj < 64; ++kj) {
      float e = esh[qi][kj];
      den += e;
      const float* vp = &vsh[kj][dq << 4];
      float4 v0 = *reinterpret_cast<const float4*>(vp + 0);
      float4 v1 = *reinterpret_cast<const float4*>(vp + 4);
      float4 v2 = *reinterpret_cast<const float4*>(vp + 8);
      float4 v3 = *reinterpret_cast<const float4*>(vp + 12);
      accv[0]  = fmaf(e, v0.x, accv[0]);  accv[1]  = fmaf(e, v0.y, accv[1]);
      accv[2]  = fmaf(e, v0.z, accv[2]);  accv[3]  = fmaf(e, v0.w, accv[3]);
      accv[4]  = fmaf(e, v1.x, accv[4]);  accv[5]  = fmaf(e, v1.y, accv[5]);
      accv[6]  = fmaf(e, v1.z, accv[6]);  accv[7]  = fmaf(e, v1.w, accv[7]);
      accv[8]  = fmaf(e, v2.x, accv[8]);  accv[9]  = fmaf(e, v2.y, accv[9]);
      accv[10] = fmaf(e, v2.z, accv[10]); accv[11] = fmaf(e, v2.w, accv[11]);
      accv[12] = fmaf(e, v3.x, accv[12]); accv[13] = fmaf(e, v3.y, accv[13]);
      accv[14] = fmaf(e, v3.z, accv[14]); accv[15] = fmaf(e, v3.w, accv[15]);
    }
  }

  float rden = 1.0f / den;
  float* op = O + ((size_t)(b * S_ + q0 + qi) * H_ + h) * D_ + (dq << 4);
  *reinterpret_cast<float4*>(op + 0)  = make_float4(accv[0]*rden,  accv[1]*rden,  accv[2]*rden,  accv[3]*rden);
  *reinterpret_cast<float4*>(op + 4)  = make_float4(accv[4]*rden,  accv[5]*rden,  accv[6]*rden,  accv[7]*rden);
  *reinterpret_cast<float4*>(op + 8)  = make_float4(accv[8]*rden,  accv[9]*rden,  accv[10]*rden, accv[11]*rden);
  *reinterpret_cast<float4*>(op + 12) = make_float4(accv[12]*rden, accv[13]*rden, accv[14]*rden, accv[15]*rden);
}

// ---------------------------------------------------------------------------
extern "C" void kernel_launch(void* const* d_in, const int* in_sizes, int n_in,
                              void* d_out, int out_size, void* d_ws, size_t ws_size,
                              hipStream_t stream) {
  const float* x    = (const float*)d_in[0];
  const float* Wq   = (const float*)d_in[1];
  const float* Wk   = (const float*)d_in[2];
  const float* Wv   = (const float*)d_in[3];
  const float* Wo   = (const float*)d_in[4];
  const float* tpl  = (const float*)d_in[5];
  const float* proj = (const float*)d_in[6];
  float* out = (float*)d_out;

  char* ws = (char*)d_ws;
  size_t off = 0;
  auto alloc = [&](size_t bytes) {
    void* p = ws + off;
    off += (bytes + 255) & ~(size_t)255;
    return p;
  };
  // ws usage: ~16.3 MB total (Abuf + qs + ks + obuf). V lives in d_out
  // (fully rewritten by the final GEMM every call -> deterministic).
  float* Abuf = (float*)alloc((size_t)H_ * T_ * D_ * 4);
  float* qs   = (float*)alloc((size_t)B_ * H_ * S_ * T_ * 4);
  float* ks   = (float*)alloc((size_t)B_ * H_ * S_ * T_ * 4);
  float* obuf = (float*)alloc((size_t)B_ * S_ * E_ * 4);
  float* vbuf = out;   // V staged in d_out, consumed by attention, then overwritten

  k_prep_A<<<dim3(H_ * T_), dim3(64), 0, stream>>>(tpl, proj, Abuf);
  k_gemm_qkv<<<dim3(E_ / 64, (B_ * S_) / 64, 3), dim3(256), 0, stream>>>(
      x, Wq, Wk, Wv, Abuf, qs, ks, vbuf);
  k_attention<<<dim3(S_ / 64, B_ * H_), dim3(256), 0, stream>>>(qs, ks, vbuf, obuf);
  k_gemm<<<dim3(E_ / 64, (B_ * S_) / 64), dim3(256), 0, stream>>>(obuf, Wo, out);
}

// Round 3
// 320.209 us; speedup vs baseline: 1.3913x; 1.3913x over previous
//
#include <hip/hip_runtime.h>
#include <math.h>

#define S_ 1024
#define T_ 32
#define SCALE_F 0.7071067811865476f

typedef unsigned int uint;
typedef unsigned short ushort;
typedef __bf16 bf16x8 __attribute__((ext_vector_type(8)));
typedef float f32x16 __attribute__((ext_vector_type(16)));

union FragU { uint4 q; bf16x8 v; };

#define MFMA(a, b, c) __builtin_amdgcn_mfma_f32_32x32x16_bf16((a), (b), (c), 0, 0, 0)

__device__ __forceinline__ uint rne16(float f) {
  uint u = __builtin_bit_cast(uint, f);
  u += 0x7fffu + ((u >> 16) & 1u);
  return u >> 16;
}

// exact truncation split: f = hi + rem, lo = trunc-bf16(rem); dropped lo*lo ~ 2^-16 rel
__device__ __forceinline__ void split8(const float4& A, const float4& B,
                                       uint4& hi, uint4& lo) {
  float f[8] = {A.x, A.y, A.z, A.w, B.x, B.y, B.z, B.w};
  uint h[8], m[8];
#pragma unroll
  for (int i = 0; i < 8; ++i) {
    uint u = __builtin_bit_cast(uint, f[i]);
    h[i] = u >> 16;
    float fh = __builtin_bit_cast(float, u & 0xffff0000u);
    m[i] = __builtin_bit_cast(uint, f[i] - fh) >> 16;
  }
  hi = make_uint4(h[0] | (h[1] << 16), h[2] | (h[3] << 16),
                  h[4] | (h[5] << 16), h[6] | (h[7] << 16));
  lo = make_uint4(m[0] | (m[1] << 16), m[2] | (m[3] << 16),
                  m[4] | (m[5] << 16), m[6] | (m[7] << 16));
}

__device__ __forceinline__ void split8a(const float* f, uint4& hi, uint4& lo) {
  uint h[8], m[8];
#pragma unroll
  for (int i = 0; i < 8; ++i) {
    uint u = __builtin_bit_cast(uint, f[i]);
    h[i] = u >> 16;
    float fh = __builtin_bit_cast(float, u & 0xffff0000u);
    m[i] = __builtin_bit_cast(uint, f[i] - fh) >> 16;
  }
  hi = make_uint4(h[0] | (h[1] << 16), h[2] | (h[3] << 16),
                  h[4] | (h[5] << 16), h[6] | (h[7] << 16));
  lo = make_uint4(m[0] | (m[1] << 16), m[2] | (m[3] << 16),
                  m[4] | (m[5] << 16), m[6] | (m[7] << 16));
}

__device__ __forceinline__ uint4 rne8(const float4& A, const float4& B) {
  float f[8] = {A.x, A.y, A.z, A.w, B.x, B.y, B.z, B.w};
  uint h[8];
#pragma unroll
  for (int i = 0; i < 8; ++i) h[i] = rne16(f[i]);
  return make_uint4(h[0] | (h[1] << 16), h[2] | (h[3] << 16),
                    h[4] | (h[5] << 16), h[6] | (h[7] << 16));
}

// ---------------------------------------------------------------------------
// cos/sin table: cs[s][2p] = cos(s*invf[p]), cs[s][2p+1] = sin(...)
// ---------------------------------------------------------------------------
__global__ __launch_bounds__(64) void k_cs(float* __restrict__ cs) {
  int s = blockIdx.x * 2 + (threadIdx.x >> 5);
  int p = threadIdx.x & 31;
  float invf = powf(10000.0f, (-2.0f * p) / 64.0f);
  float sn, c;
  sincosf((float)s * invf, &sn, &c);
  cs[s * 64 + 2 * p] = c;
  cs[s * 64 + 2 * p + 1] = sn;
}

// ---------------------------------------------------------------------------
// A[h,t,i] = (1/8) * sum_j proj[h,j] * tpl_norm[h,t,(i-j) mod 64]  -> hi/lo bf16
// ---------------------------------------------------------------------------
__global__ __launch_bounds__(64) void k_prep_A(const float* __restrict__ tpl,
                                               const float* __restrict__ proj,
                                               ushort* __restrict__ Ahh,
                                               ushort* __restrict__ Ahl) {
  int ht = blockIdx.x;  // h*32 + t
  int h = ht >> 5;
  int lane = threadIdx.x;
  float tv = tpl[ht * 64 + lane];
  float ss = tv * tv;
#pragma unroll
  for (int off = 1; off < 64; off <<= 1) ss += __shfl_xor(ss, off);
  float rn = 1.0f / fmaxf(sqrtf(ss), 1e-12f);
  __shared__ float tn[64];
  tn[lane] = tv * rn;
  __syncthreads();
  float acc = 0.f;
#pragma unroll
  for (int j = 0; j < 64; ++j) acc += proj[h * 64 + j] * tn[(lane - j) & 63];
  float v = acc * 0.125f;
  uint u = __builtin_bit_cast(uint, v);
  uint hi = u >> 16;
  float fh = __builtin_bit_cast(float, u & 0xffff0000u);
  uint lo = __builtin_bit_cast(uint, v - fh) >> 16;
  Ahh[ht * 64 + lane] = (ushort)hi;
  Ahl[ht * 64 + lane] = (ushort)lo;
}

// ---------------------------------------------------------------------------
// Fused QKV MFMA GEMM. Tile 128x64, BK=32, 256 thr = 4 waves (2 row x 2 col),
// wave tile 64x32 via 2 x mfma_f32_32x32x16_bf16 frags.
// z<2 (Q/K): hi/lo 3-product (fp32-quality) + MFMA RoPE/signature epilogue.
// z==2 (V): RNE bf16 single product, store f32 V to Vout ([b][s][h][d]).
// ---------------------------------------------------------------------------
__global__ __launch_bounds__(256) void k_qkv(
    const float* __restrict__ X,
    const float* __restrict__ Wq, const float* __restrict__ Wk,
    const float* __restrict__ Wv,
    const ushort* __restrict__ Ahh, const ushort* __restrict__ Ahl,
    const float* __restrict__ cs,
    float* __restrict__ Qs, float* __restrict__ Ks, float* __restrict__ Vout) {
  // union: staging (A hi/lo 8KB+8KB, B hi/lo 4KB+4KB) | dump [2][64][68] f32
  __shared__ __align__(16) char smem[34816];

  const int z = blockIdx.z;
  const float* Wm = (z == 0) ? Wq : (z == 1) ? Wk : Wv;
  const int m0 = blockIdx.y * 128;
  const int n0 = blockIdx.x * 64;
  const int h = blockIdx.x;

  const int tid = threadIdx.x;
  const int l = tid & 63;
  const int wid = tid >> 6;
  const int wr = wid >> 1, wc = wid & 1;
  const int l31 = l & 31, lhi = l >> 5;

  const int sr = tid >> 2;  // staging row 0..63
  const int sc = tid & 3;   // staging 16B col 0..3

  f32x16 acc0 = 0.0f, acc1 = 0.0f;

  for (int k0 = 0; k0 < 1024; k0 += 32) {
    float4 a0[2], a1[2], b0, b1;
#pragma unroll
    for (int sl = 0; sl < 2; ++sl) {
      const float* ap = X + (size_t)(m0 + sr + 64 * sl) * 1024 + k0 + sc * 8;
      a0[sl] = *reinterpret_cast<const float4*>(ap);
      a1[sl] = *reinterpret_cast<const float4*>(ap + 4);
    }
    {
      const float* bp = Wm + (size_t)(n0 + sr) * 1024 + k0 + sc * 8;
      b0 = *reinterpret_cast<const float4*>(bp);
      b1 = *reinterpret_cast<const float4*>(bp + 4);
    }
    __syncthreads();
    if (z < 2) {
#pragma unroll
      for (int sl = 0; sl < 2; ++sl) {
        uint4 hi, lo;
        split8(a0[sl], a1[sl], hi, lo);
        int row = sr + 64 * sl;
        int off = row * 64 + ((sc ^ ((row >> 1) & 3)) << 4);
        *reinterpret_cast<uint4*>(smem + off) = hi;
        *reinterpret_cast<uint4*>(smem + 8192 + off) = lo;
      }
      {
        uint4 hi, lo;
        split8(b0, b1, hi, lo);
        int off = sr * 64 + ((sc ^ ((sr >> 1) & 3)) << 4);
        *reinterpret_cast<uint4*>(smem + 16384 + off) = hi;
        *reinterpret_cast<uint4*>(smem + 20480 + off) = lo;
      }
    } else {
#pragma unroll
      for (int sl = 0; sl < 2; ++sl) {
        int row = sr + 64 * sl;
        int off = row * 64 + ((sc ^ ((row >> 1) & 3)) << 4);
        *reinterpret_cast<uint4*>(smem + off) = rne8(a0[sl], a1[sl]);
      }
      int off = sr * 64 + ((sc ^ ((sr >> 1) & 3)) << 4);
      *reinterpret_cast<uint4*>(smem + 16384 + off) = rne8(b0, b1);
    }
    __syncthreads();

#pragma unroll
    for (int kst = 0; kst < 2; ++kst) {
      FragU ah[2], al[2], bh, bl;
#pragma unroll
      for (int fm = 0; fm < 2; ++fm) {
        int row = wr * 64 + fm * 32 + l31;
        int cc = (kst * 2 + lhi) ^ ((row >> 1) & 3);
        ah[fm].q = *reinterpret_cast<const uint4*>(smem + row * 64 + cc * 16);
        if (z < 2)
          al[fm].q =
              *reinterpret_cast<const uint4*>(smem + 8192 + row * 64 + cc * 16);
      }
      {
        int brow = wc * 32 + l31;
        int bcc = (kst * 2 + lhi) ^ ((brow >> 1) & 3);
        bh.q =
            *reinterpret_cast<const uint4*>(smem + 16384 + brow * 64 + bcc * 16);
        if (z < 2)
          bl.q = *reinterpret_cast<const uint4*>(smem + 20480 + brow * 64 +
                                                 bcc * 16);
      }
      if (z < 2) {
        acc0 = MFMA(al[0].v, bh.v, acc0);
        acc0 = MFMA(ah[0].v, bl.v, acc0);
        acc1 = MFMA(al[1].v, bh.v, acc1);
        acc1 = MFMA(ah[1].v, bl.v, acc1);
      }
      acc0 = MFMA(ah[0].v, bh.v, acc0);
      acc1 = MFMA(ah[1].v, bh.v, acc1);
    }
  }

  if (z == 2) {
    // V store: [b*1024+s == m][h][d]
#pragma unroll
    for (int fm = 0; fm < 2; ++fm) {
      const f32x16& a = fm ? acc1 : acc0;
#pragma unroll
      for (int j = 0; j < 16; ++j) {
        int rl = fm * 32 + (j & 3) + ((j >> 2) & 3) * 8 + 4 * lhi;
        int m = m0 + wr * 64 + rl;
        int d = wc * 32 + l31;
        Vout[((size_t)m * 16 + h) * 64 + d] = a[j];
      }
    }
    return;
  }

  float* Sig = (z == 0) ? Qs : Ks;
  float* dmp = reinterpret_cast<float*>(smem);  // [2][64][68]
  __syncthreads();
#pragma unroll
  for (int fm = 0; fm < 2; ++fm) {
    const f32x16& a = fm ? acc1 : acc0;
#pragma unroll
    for (int j = 0; j < 16; ++j) {
      int rl = fm * 32 + (j & 3) + ((j >> 2) & 3) * 8 + 4 * lhi;
      dmp[(wr * 64 + rl) * 68 + wc * 32 + l31] = a[j];
    }
  }
  __syncthreads();

  // signature: rows wr*64 + wc*32 + (l&31); RoPE in-lane; 3-product MFMA vs Ah
  int srow = wr * 64 + wc * 32 + l31;
  int sq = (m0 + srow) & 1023;
  f32x16 sacc = 0.0f;
#pragma unroll
  for (int kst = 0; kst < 4; ++kst) {
    const float* dp = &dmp[srow * 68 + kst * 16 + lhi * 8];
    float4 x0 = *reinterpret_cast<const float4*>(dp);
    float4 x1 = *reinterpret_cast<const float4*>(dp + 4);
    const float* cp = &cs[sq * 64 + kst * 16 + lhi * 8];
    float4 c0 = *reinterpret_cast<const float4*>(cp);
    float4 c1 = *reinterpret_cast<const float4*>(cp + 4);
    float r[8];
    r[0] = x0.x * c0.x - x0.y * c0.y;
    r[1] = x0.x * c0.y + x0.y * c0.x;
    r[2] = x0.z * c0.z - x0.w * c0.w;
    r[3] = x0.z * c0.w + x0.w * c0.z;
    r[4] = x1.x * c1.x - x1.y * c1.y;
    r[5] = x1.x * c1.y + x1.y * c1.x;
    r[6] = x1.z * c1.z - x1.w * c1.w;
    r[7] = x1.z * c1.w + x1.w * c1.z;
    FragU ah, al;
    split8a(r, ah.q, al.q);
    size_t boff = ((size_t)(h * 32 + l31) * 64 + kst * 16 + lhi * 8);
    FragU bh, bl;
    bh.q = *reinterpret_cast<const uint4*>(Ahh + boff);
    bl.q = *reinterpret_cast<const uint4*>(Ahl + boff);
    sacc = MFMA(al.v, bh.v, sacc);
    sacc = MFMA(ah.v, bl.v, sacc);
    sacc = MFMA(ah.v, bh.v, sacc);
  }
#pragma unroll
  for (int j = 0; j < 16; ++j) {
    float v = sacc[j];
    float ss = v * v;
    ss += __shfl_xor(ss, 1);
    ss += __shfl_xor(ss, 2);
    ss += __shfl_xor(ss, 4);
    ss += __shfl_xor(ss, 8);
    ss += __shfl_xor(ss, 16);
    float rn = 1.0f / fmaxf(sqrtf(ss), 1e-12f);
    int rl = (j & 3) + ((j >> 2) & 3) * 8 + 4 * lhi;
    int m = m0 + wr * 64 + wc * 32 + rl;
    int bb = m >> 10, s2 = m & 1023;
    Sig[(((size_t)(bb * 16 + h)) * 1024 + s2) * 32 + l31] = v * rn;
  }
}

// ---------------------------------------------------------------------------
// Final projection: Y[m][n] = sum_k obuf_bf16[m][k] * Wo[n][k]; single product
// ---------------------------------------------------------------------------
__global__ __launch_bounds__(256) void k_final(const ushort* __restrict__ Xb,
                                               const float* __restrict__ W,
                                               float* __restrict__ Y) {
  __shared__ __align__(16) char smem[12288];  // A bf16 8KB + B bf16 4KB

  const int m0 = blockIdx.y * 128;
  const int n0 = blockIdx.x * 64;
  const int tid = threadIdx.x;
  const int l = tid & 63;
  const int wid = tid >> 6;
  const int wr = wid >> 1, wc = wid & 1;
  const int l31 = l & 31, lhi = l >> 5;
  const int sr = tid >> 2;
  const int sc = tid & 3;

  f32x16 acc0 = 0.0f, acc1 = 0.0f;

  for (int k0 = 0; k0 < 1024; k0 += 32) {
    uint4 av[2];
    float4 b0, b1;
#pragma unroll
    for (int sl = 0; sl < 2; ++sl)
      av[sl] = *reinterpret_cast<const uint4*>(
          Xb + (size_t)(m0 + sr + 64 * sl) * 1024 + k0 + sc * 8);
    {
      const float* bp = W + (size_t)(n0 + sr) * 1024 + k0 + sc * 8;
      b0 = *reinterpret_cast<const float4*>(bp);
      b1 = *reinterpret_cast<const float4*>(bp + 4);
    }
    __syncthreads();
#pragma unroll
    for (int sl = 0; sl < 2; ++sl) {
      int row = sr + 64 * sl;
      int off = row * 64 + ((sc ^ ((row >> 1) & 3)) << 4);
      *reinterpret_cast<uint4*>(smem + off) = av[sl];
    }
    {
      int off = sr * 64 + ((sc ^ ((sr >> 1) & 3)) << 4);
      *reinterpret_cast<uint4*>(smem + 8192 + off) = rne8(b0, b1);
    }
    __syncthreads();

#pragma unroll
    for (int kst = 0; kst < 2; ++kst) {
      FragU ah[2], bh;
#pragma unroll
      for (int fm = 0; fm < 2; ++fm) {
        int row = wr * 64 + fm * 32 + l31;
        int cc = (kst * 2 + lhi) ^ ((row >> 1) & 3);
        ah[fm].q = *reinterpret_cast<const uint4*>(smem + row * 64 + cc * 16);
      }
      int brow = wc * 32 + l31;
      int bcc = (kst * 2 + lhi) ^ ((brow >> 1) & 3);
      bh.q = *reinterpret_cast<const uint4*>(smem + 8192 + brow * 64 + bcc * 16);
      acc0 = MFMA(ah[0].v, bh.v, acc0);
      acc1 = MFMA(ah[1].v, bh.v, acc1);
    }
  }

#pragma unroll
  for (int fm = 0; fm < 2; ++fm) {
    const f32x16& a = fm ? acc1 : acc0;
#pragma unroll
    for (int j = 0; j < 16; ++j) {
      int rl = fm * 32 + (j & 3) + ((j >> 2) & 3) * 8 + 4 * lhi;
      int m = m0 + wr * 64 + rl;
      Y[(size_t)m * 1024 + n0 + wc * 32 + l31] = a[j];
    }
  }
}

// ---------------------------------------------------------------------------
// Attention (unchanged math): per (b,h), 64-query tile; scores bounded -> no
// max subtraction. Output written as bf16 (RNE) for the final MFMA GEMM.
// ---------------------------------------------------------------------------
__global__ __launch_bounds__(256) void k_attention(const float* __restrict__ Qs,
                                                   const float* __restrict__ Ks,
                                                   const float* __restrict__ V,
                                                   ushort* __restrict__ O) {
  __shared__ float qsh[64][36];
  __shared__ float ksh[32][68];
  __shared__ float vsh[64][64];
  __shared__ float esh[64][68];

  int tid = threadIdx.x;
  int bh = blockIdx.y;
  int b = bh >> 4, h = bh & 15;
  int q0 = blockIdx.x << 6;
  const float* qsig = Qs + (size_t)(bh * S_ + q0) * T_;
  const float* ksig = Ks + (size_t)bh * S_ * T_;

  for (int i = tid; i < 512; i += 256) {
    int r = i >> 3, c = (i & 7) << 2;
    *reinterpret_cast<float4*>(&qsh[r][c]) =
        *reinterpret_cast<const float4*>(&qsig[r * 32 + c]);
  }

  int tq = tid >> 4, tk = tid & 15;
  int qi = tid >> 2, dq = tid & 3;
  float accv[16] = {};
  float den = 0.f;

  for (int kt = 0; kt < 16; ++kt) {
    int k0 = kt << 6;
    __syncthreads();
    for (int i = tid; i < 512; i += 256) {
      int r = i >> 3, c = (i & 7) << 2;
      float4 kv = *reinterpret_cast<const float4*>(&ksig[(k0 + r) * 32 + c]);
      ksh[c + 0][r] = kv.x; ksh[c + 1][r] = kv.y;
      ksh[c + 2][r] = kv.z; ksh[c + 3][r] = kv.w;
    }
    for (int i = tid; i < 1024; i += 256) {
      int r = i >> 4, c = (i & 15) << 2;
      *reinterpret_cast<float4*>(&vsh[r][c]) = *reinterpret_cast<const float4*>(
          &V[((size_t)(b * S_ + k0 + r) * 16 + h) * 64 + c]);
    }
    __syncthreads();

    float sc[4][4] = {};
#pragma unroll
    for (int t4 = 0; t4 < 32; t4 += 4) {
      float4 qv[4], kv[4];
#pragma unroll
      for (int i = 0; i < 4; ++i)
        qv[i] = *reinterpret_cast<const float4*>(&qsh[(tq << 2) + i][t4]);
#pragma unroll
      for (int tt = 0; tt < 4; ++tt)
        kv[tt] = *reinterpret_cast<const float4*>(&ksh[t4 + tt][tk << 2]);
#pragma unroll
      for (int i = 0; i < 4; ++i) {
        float qa[4] = {qv[i].x, qv[i].y, qv[i].z, qv[i].w};
#pragma unroll
        for (int tt = 0; tt < 4; ++tt) {
          float kb[4] = {kv[tt].x, kv[tt].y, kv[tt].z, kv[tt].w};
          sc[i][0] = fmaf(qa[tt], kb[0], sc[i][0]);
          sc[i][1] = fmaf(qa[tt], kb[1], sc[i][1]);
          sc[i][2] = fmaf(qa[tt], kb[2], sc[i][2]);
          sc[i][3] = fmaf(qa[tt], kb[3], sc[i][3]);
        }
      }
    }
#pragma unroll
    for (int i = 0; i < 4; ++i) {
      float4 ev;
      ev.x = __expf(sc[i][0] * SCALE_F);
      ev.y = __expf(sc[i][1] * SCALE_F);
      ev.z = __expf(sc[i][2] * SCALE_F);
      ev.w = __expf(sc[i][3] * SCALE_F);
      *reinterpret_cast<float4*>(&esh[(tq << 2) + i][tk << 2]) = ev;
    }
    __syncthreads();

    for (int kj = 0; kj < 64; ++kj) {
      float e = esh[qi][kj];
      den += e;
      const float* vp = &vsh[kj][dq << 4];
      float4 v0 = *reinterpret_cast<const float4*>(vp + 0);
      float4 v1 = *reinterpret_cast<const float4*>(vp + 4);
      float4 v2 = *reinterpret_cast<const float4*>(vp + 8);
      float4 v3 = *reinterpret_cast<const float4*>(vp + 12);
      accv[0]  = fmaf(e, v0.x, accv[0]);  accv[1]  = fmaf(e, v0.y, accv[1]);
      accv[2]  = fmaf(e, v0.z, accv[2]);  accv[3]  = fmaf(e, v0.w, accv[3]);
      accv[4]  = fmaf(e, v1.x, accv[4]);  accv[5]  = fmaf(e, v1.y, accv[5]);
      accv[6]  = fmaf(e, v1.z, accv[6]);  accv[7]  = fmaf(e, v1.w, accv[7]);
      accv[8]  = fmaf(e, v2.x, accv[8]);  accv[9]  = fmaf(e, v2.y, accv[9]);
      accv[10] = fmaf(e, v2.z, accv[10]); accv[11] = fmaf(e, v2.w, accv[11]);
      accv[12] = fmaf(e, v3.x, accv[12]); accv[13] = fmaf(e, v3.y, accv[13]);
      accv[14] = fmaf(e, v3.z, accv[14]); accv[15] = fmaf(e, v3.w, accv[15]);
    }
  }

  float rden = 1.0f / den;
  uint pk[8];
#pragma unroll
  for (int w = 0; w < 8; ++w)
    pk[w] = rne16(accv[2 * w] * rden) | (rne16(accv[2 * w + 1] * rden) << 16);
  size_t idx = ((size_t)(b * S_ + q0 + qi) * 16 + h) * 64 + (dq << 4);
  *reinterpret_cast<uint4*>(O + idx) = make_uint4(pk[0], pk[1], pk[2], pk[3]);
  *reinterpret_cast<uint4*>(O + idx + 8) = make_uint4(pk[4], pk[5], pk[6], pk[7]);
}

// ---------------------------------------------------------------------------
extern "C" void kernel_launch(void* const* d_in, const int* in_sizes, int n_in,
                              void* d_out, int out_size, void* d_ws,
                              size_t ws_size, hipStream_t stream) {
  const float* x = (const float*)d_in[0];
  const float* Wq = (const float*)d_in[1];
  const float* Wk = (const float*)d_in[2];
  const float* Wv = (const float*)d_in[3];
  const float* Wo = (const float*)d_in[4];
  const float* tpl = (const float*)d_in[5];
  const float* proj = (const float*)d_in[6];
  float* out = (float*)d_out;

  char* ws = (char*)d_ws;
  size_t off = 0;
  auto alloc = [&](size_t bytes) {
    void* p = ws + off;
    off += (bytes + 255) & ~(size_t)255;
    return p;
  };
  // ws: cs 256KB + Ah 128KB + qs/ks 8MB + obuf 4MB  (~12.4 MB total)
  float* cs = (float*)alloc((size_t)1024 * 64 * 4);
  ushort* Ahh = (ushort*)alloc((size_t)16 * 32 * 64 * 2);
  ushort* Ahl = (ushort*)alloc((size_t)16 * 32 * 64 * 2);
  float* qs = (float*)alloc((size_t)32 * 1024 * 32 * 4);
  float* ks = (float*)alloc((size_t)32 * 1024 * 32 * 4);
  ushort* obuf = (ushort*)alloc((size_t)2 * 1024 * 1024 * 2);
  float* vbuf = out;  // V staged in d_out; consumed by attention, overwritten

  k_cs<<<dim3(512), dim3(64), 0, stream>>>(cs);
  k_prep_A<<<dim3(512), dim3(64), 0, stream>>>(tpl, proj, Ahh, Ahl);
  k_qkv<<<dim3(16, 16, 3), dim3(256), 0, stream>>>(x, Wq, Wk, Wv, Ahh, Ahl, cs,
                                                   qs, ks, vbuf);
  k_attention<<<dim3(16, 32), dim3(256), 0, stream>>>(qs, ks, vbuf, obuf);
  k_final<<<dim3(16, 16), dim3(256), 0, stream>>>(obuf, Wo, out);
}

// Round 4
// 154.583 us; speedup vs baseline: 2.8820x; 2.0714x over previous
//
#include <hip/hip_runtime.h>
#include <math.h>

#define S_ 1024
#define T_ 32
#define SCALE_F 0.7071067811865476f

typedef unsigned int uint;
typedef unsigned short ushort;
typedef __bf16 bf16x8 __attribute__((ext_vector_type(8)));
typedef float f32x16 __attribute__((ext_vector_type(16)));

union FragU { uint4 q; bf16x8 v; };

#define MFMA(a, b, c) __builtin_amdgcn_mfma_f32_32x32x16_bf16((a), (b), (c), 0, 0, 0)

__device__ __forceinline__ uint rne16(float f) {
  uint u = __builtin_bit_cast(uint, f);
  u += 0x7fffu + ((u >> 16) & 1u);
  return u >> 16;
}

// exact truncation split: f = hi + rem, lo = trunc-bf16(rem)
__device__ __forceinline__ void split8(const float4& A, const float4& B,
                                       uint4& hi, uint4& lo) {
  float f[8] = {A.x, A.y, A.z, A.w, B.x, B.y, B.z, B.w};
  uint h[8], m[8];
#pragma unroll
  for (int i = 0; i < 8; ++i) {
    uint u = __builtin_bit_cast(uint, f[i]);
    h[i] = u >> 16;
    float fh = __builtin_bit_cast(float, u & 0xffff0000u);
    m[i] = __builtin_bit_cast(uint, f[i] - fh) >> 16;
  }
  hi = make_uint4(h[0] | (h[1] << 16), h[2] | (h[3] << 16),
                  h[4] | (h[5] << 16), h[6] | (h[7] << 16));
  lo = make_uint4(m[0] | (m[1] << 16), m[2] | (m[3] << 16),
                  m[4] | (m[5] << 16), m[6] | (m[7] << 16));
}

__device__ __forceinline__ void split8a(const float* f, uint4& hi, uint4& lo) {
  uint h[8], m[8];
#pragma unroll
  for (int i = 0; i < 8; ++i) {
    uint u = __builtin_bit_cast(uint, f[i]);
    h[i] = u >> 16;
    float fh = __builtin_bit_cast(float, u & 0xffff0000u);
    m[i] = __builtin_bit_cast(uint, f[i] - fh) >> 16;
  }
  hi = make_uint4(h[0] | (h[1] << 16), h[2] | (h[3] << 16),
                  h[4] | (h[5] << 16), h[6] | (h[7] << 16));
  lo = make_uint4(m[0] | (m[1] << 16), m[2] | (m[3] << 16),
                  m[4] | (m[5] << 16), m[6] | (m[7] << 16));
}

__device__ __forceinline__ uint4 rne8(const float4& A, const float4& B) {
  float f[8] = {A.x, A.y, A.z, A.w, B.x, B.y, B.z, B.w};
  uint h[8];
#pragma unroll
  for (int i = 0; i < 8; ++i) h[i] = rne16(f[i]);
  return make_uint4(h[0] | (h[1] << 16), h[2] | (h[3] << 16),
                    h[4] | (h[5] << 16), h[6] | (h[7] << 16));
}

// ---------------------------------------------------------------------------
// cos/sin table
// ---------------------------------------------------------------------------
__global__ __launch_bounds__(64) void k_cs(float* __restrict__ cs) {
  int s = blockIdx.x * 2 + (threadIdx.x >> 5);
  int p = threadIdx.x & 31;
  float invf = powf(10000.0f, (-2.0f * p) / 64.0f);
  float sn, c;
  sincosf((float)s * invf, &sn, &c);
  cs[s * 64 + 2 * p] = c;
  cs[s * 64 + 2 * p + 1] = sn;
}

// ---------------------------------------------------------------------------
// A[h,t,i] = (1/8) * sum_j proj[h,j] * tpl_norm[h,t,(i-j) mod 64]  -> hi/lo bf16
// ---------------------------------------------------------------------------
__global__ __launch_bounds__(64) void k_prep_A(const float* __restrict__ tpl,
                                               const float* __restrict__ proj,
                                               ushort* __restrict__ Ahh,
                                               ushort* __restrict__ Ahl) {
  int ht = blockIdx.x;  // h*32 + t
  int h = ht >> 5;
  int lane = threadIdx.x;
  float tv = tpl[ht * 64 + lane];
  float ss = tv * tv;
#pragma unroll
  for (int off = 1; off < 64; off <<= 1) ss += __shfl_xor(ss, off);
  float rn = 1.0f / fmaxf(sqrtf(ss), 1e-12f);
  __shared__ float tn[64];
  tn[lane] = tv * rn;
  __syncthreads();
  float acc = 0.f;
#pragma unroll
  for (int j = 0; j < 64; ++j) acc += proj[h * 64 + j] * tn[(lane - j) & 63];
  float v = acc * 0.125f;
  uint u = __builtin_bit_cast(uint, v);
  uint hi = u >> 16;
  float fh = __builtin_bit_cast(float, u & 0xffff0000u);
  uint lo = __builtin_bit_cast(uint, v - fh) >> 16;
  Ahh[ht * 64 + lane] = (ushort)hi;
  Ahl[ht * 64 + lane] = (ushort)lo;
}

// ---------------------------------------------------------------------------
// Fused QKV MFMA GEMM (core unchanged from validated round-3 kernel).
// z<2: hi/lo 3-product + RoPE/signature epilogue -> Sig stored bf16.
// z==2: single product -> V stored TRANSPOSED bf16: Vt[b][h][d][s].
// ---------------------------------------------------------------------------
__global__ __launch_bounds__(256) void k_qkv(
    const float* __restrict__ X,
    const float* __restrict__ Wq, const float* __restrict__ Wk,
    const float* __restrict__ Wv,
    const ushort* __restrict__ Ahh, const ushort* __restrict__ Ahl,
    const float* __restrict__ cs,
    ushort* __restrict__ Qs, ushort* __restrict__ Ks,
    ushort* __restrict__ Vt) {
  __shared__ __align__(16) char smem[34816];

  const int z = blockIdx.z;
  const float* Wm = (z == 0) ? Wq : (z == 1) ? Wk : Wv;
  const int m0 = blockIdx.y * 128;
  const int n0 = blockIdx.x * 64;
  const int h = blockIdx.x;

  const int tid = threadIdx.x;
  const int l = tid & 63;
  const int wid = tid >> 6;
  const int wr = wid >> 1, wc = wid & 1;
  const int l31 = l & 31, lhi = l >> 5;

  const int sr = tid >> 2;
  const int sc = tid & 3;

  f32x16 acc0 = 0.0f, acc1 = 0.0f;

  for (int k0 = 0; k0 < 1024; k0 += 32) {
    float4 a0[2], a1[2], b0, b1;
#pragma unroll
    for (int sl = 0; sl < 2; ++sl) {
      const float* ap = X + (size_t)(m0 + sr + 64 * sl) * 1024 + k0 + sc * 8;
      a0[sl] = *reinterpret_cast<const float4*>(ap);
      a1[sl] = *reinterpret_cast<const float4*>(ap + 4);
    }
    {
      const float* bp = Wm + (size_t)(n0 + sr) * 1024 + k0 + sc * 8;
      b0 = *reinterpret_cast<const float4*>(bp);
      b1 = *reinterpret_cast<const float4*>(bp + 4);
    }
    __syncthreads();
    if (z < 2) {
#pragma unroll
      for (int sl = 0; sl < 2; ++sl) {
        uint4 hi, lo;
        split8(a0[sl], a1[sl], hi, lo);
        int row = sr + 64 * sl;
        int off = row * 64 + ((sc ^ ((row >> 1) & 3)) << 4);
        *reinterpret_cast<uint4*>(smem + off) = hi;
        *reinterpret_cast<uint4*>(smem + 8192 + off) = lo;
      }
      {
        uint4 hi, lo;
        split8(b0, b1, hi, lo);
        int off = sr * 64 + ((sc ^ ((sr >> 1) & 3)) << 4);
        *reinterpret_cast<uint4*>(smem + 16384 + off) = hi;
        *reinterpret_cast<uint4*>(smem + 20480 + off) = lo;
      }
    } else {
#pragma unroll
      for (int sl = 0; sl < 2; ++sl) {
        int row = sr + 64 * sl;
        int off = row * 64 + ((sc ^ ((row >> 1) & 3)) << 4);
        *reinterpret_cast<uint4*>(smem + off) = rne8(a0[sl], a1[sl]);
      }
      int off = sr * 64 + ((sc ^ ((sr >> 1) & 3)) << 4);
      *reinterpret_cast<uint4*>(smem + 16384 + off) = rne8(b0, b1);
    }
    __syncthreads();

#pragma unroll
    for (int kst = 0; kst < 2; ++kst) {
      FragU ah[2], al[2], bh, bl;
#pragma unroll
      for (int fm = 0; fm < 2; ++fm) {
        int row = wr * 64 + fm * 32 + l31;
        int cc = (kst * 2 + lhi) ^ ((row >> 1) & 3);
        ah[fm].q = *reinterpret_cast<const uint4*>(smem + row * 64 + cc * 16);
        if (z < 2)
          al[fm].q =
              *reinterpret_cast<const uint4*>(smem + 8192 + row * 64 + cc * 16);
      }
      {
        int brow = wc * 32 + l31;
        int bcc = (kst * 2 + lhi) ^ ((brow >> 1) & 3);
        bh.q =
            *reinterpret_cast<const uint4*>(smem + 16384 + brow * 64 + bcc * 16);
        if (z < 2)
          bl.q = *reinterpret_cast<const uint4*>(smem + 20480 + brow * 64 +
                                                 bcc * 16);
      }
      if (z < 2) {
        acc0 = MFMA(al[0].v, bh.v, acc0);
        acc0 = MFMA(ah[0].v, bl.v, acc0);
        acc1 = MFMA(al[1].v, bh.v, acc1);
        acc1 = MFMA(ah[1].v, bl.v, acc1);
      }
      acc0 = MFMA(ah[0].v, bh.v, acc0);
      acc1 = MFMA(ah[1].v, bh.v, acc1);
    }
  }

  if (z == 2) {
    // V store transposed bf16: Vt[((b*16+h)*64+d)*1024 + s]
    int d = wc * 32 + l31;
#pragma unroll
    for (int fm = 0; fm < 2; ++fm) {
      const f32x16& a = fm ? acc1 : acc0;
#pragma unroll
      for (int j = 0; j < 16; ++j) {
        int rl = fm * 32 + (j & 3) + ((j >> 2) & 3) * 8 + 4 * lhi;
        int m = m0 + wr * 64 + rl;
        int b = m >> 10, s = m & 1023;
        Vt[((size_t)((b * 16 + h) * 64 + d)) * 1024 + s] = (ushort)rne16(a[j]);
      }
    }
    return;
  }

  ushort* Sig = (z == 0) ? Qs : Ks;
  float* dmp = reinterpret_cast<float*>(smem);  // [2][64][68]
  __syncthreads();
#pragma unroll
  for (int fm = 0; fm < 2; ++fm) {
    const f32x16& a = fm ? acc1 : acc0;
#pragma unroll
    for (int j = 0; j < 16; ++j) {
      int rl = fm * 32 + (j & 3) + ((j >> 2) & 3) * 8 + 4 * lhi;
      dmp[(wr * 64 + rl) * 68 + wc * 32 + l31] = a[j];
    }
  }
  __syncthreads();

  int srow = wr * 64 + wc * 32 + l31;
  int sq = (m0 + srow) & 1023;
  f32x16 sacc = 0.0f;
#pragma unroll
  for (int kst = 0; kst < 4; ++kst) {
    const float* dp = &dmp[srow * 68 + kst * 16 + lhi * 8];
    float4 x0 = *reinterpret_cast<const float4*>(dp);
    float4 x1 = *reinterpret_cast<const float4*>(dp + 4);
    const float* cp = &cs[sq * 64 + kst * 16 + lhi * 8];
    float4 c0 = *reinterpret_cast<const float4*>(cp);
    float4 c1 = *reinterpret_cast<const float4*>(cp + 4);
    float r[8];
    r[0] = x0.x * c0.x - x0.y * c0.y;
    r[1] = x0.x * c0.y + x0.y * c0.x;
    r[2] = x0.z * c0.z - x0.w * c0.w;
    r[3] = x0.z * c0.w + x0.w * c0.z;
    r[4] = x1.x * c1.x - x1.y * c1.y;
    r[5] = x1.x * c1.y + x1.y * c1.x;
    r[6] = x1.z * c1.z - x1.w * c1.w;
    r[7] = x1.z * c1.w + x1.w * c1.z;
    FragU ah, al;
    split8a(r, ah.q, al.q);
    size_t boff = ((size_t)(h * 32 + l31) * 64 + kst * 16 + lhi * 8);
    FragU bh, bl;
    bh.q = *reinterpret_cast<const uint4*>(Ahh + boff);
    bl.q = *reinterpret_cast<const uint4*>(Ahl + boff);
    sacc = MFMA(al.v, bh.v, sacc);
    sacc = MFMA(ah.v, bl.v, sacc);
    sacc = MFMA(ah.v, bh.v, sacc);
  }
#pragma unroll
  for (int j = 0; j < 16; ++j) {
    float v = sacc[j];
    float ss = v * v;
    ss += __shfl_xor(ss, 1);
    ss += __shfl_xor(ss, 2);
    ss += __shfl_xor(ss, 4);
    ss += __shfl_xor(ss, 8);
    ss += __shfl_xor(ss, 16);
    float rn = 1.0f / fmaxf(sqrtf(ss), 1e-12f);
    int rl = (j & 3) + ((j >> 2) & 3) * 8 + 4 * lhi;
    int m = m0 + wr * 64 + wc * 32 + rl;
    int bb = m >> 10, s2 = m & 1023;
    Sig[(((size_t)(bb * 16 + h)) * 1024 + s2) * 32 + l31] =
        (ushort)rne16(v * rn);
  }
}

// ---------------------------------------------------------------------------
// MFMA attention. Grid (S/128, B*H), 256 thr = 4 waves, wave owns 32 q-rows.
// Scores via MFMA (A=Qsig, B=Ksig rows); exp on f32 acc (bounded, no max-sub);
// den accumulated in C-layout regs (reg<->q mapping identical to PV acc);
// P transposed through per-wave LDS tile (<=2-way bank aliasing);
// PV via MFMA with B = Vt rows (d-major, direct 16B global loads).
// ---------------------------------------------------------------------------
__global__ __launch_bounds__(256) void k_attn(const ushort* __restrict__ Qs,
                                              const ushort* __restrict__ Ks,
                                              const ushort* __restrict__ Vt,
                                              ushort* __restrict__ O) {
  __shared__ ushort plds[4][32][68];

  const int tid = threadIdx.x;
  const int l = tid & 63;
  const int wid = tid >> 6;
  const int l31 = l & 31, lhi = l >> 5;
  const int bh = blockIdx.y;
  const int q0 = blockIdx.x * 128 + wid * 32;

  // Q A-frags (kst = 0,1), loaded once
  FragU aq0, aq1;
  {
    const ushort* qp = Qs + ((size_t)bh * 1024 + q0 + l31) * 32 + lhi * 8;
    aq0.q = *reinterpret_cast<const uint4*>(qp);
    aq1.q = *reinterpret_cast<const uint4*>(qp + 16);
  }

  const ushort* kbase = Ks + (size_t)bh * 1024 * 32;
  const ushort* vbase = Vt + (size_t)bh * 64 * 1024;

  f32x16 oacc0 = 0.0f, oacc1 = 0.0f;
  float pden[16];
#pragma unroll
  for (int r = 0; r < 16; ++r) pden[r] = 0.f;

  for (int kt = 0; kt < 16; ++kt) {
    const int k0 = kt * 64;
    // ---- scores: S[32q][64key] = 2 ntiles x 2 ksteps ----
    f32x16 sacc[2];
    sacc[0] = 0.0f;
    sacc[1] = 0.0f;
#pragma unroll
    for (int nt = 0; nt < 2; ++nt) {
      const ushort* kp = kbase + (size_t)(k0 + nt * 32 + l31) * 32 + lhi * 8;
      FragU b0, b1;
      b0.q = *reinterpret_cast<const uint4*>(kp);
      b1.q = *reinterpret_cast<const uint4*>(kp + 16);
      sacc[nt] = MFMA(aq0.v, b0.v, sacc[nt]);
      sacc[nt] = MFMA(aq1.v, b1.v, sacc[nt]);
    }
    // ---- exp -> den + bf16 P into per-wave LDS (transpose) ----
#pragma unroll
    for (int nt = 0; nt < 2; ++nt) {
#pragma unroll
      for (int r = 0; r < 16; ++r) {
        float e = __expf(sacc[nt][r] * SCALE_F);
        pden[r] += e;
        int q = (r & 3) + ((r >> 2) << 3) + 4 * lhi;
        plds[wid][q][nt * 32 + l31] = (ushort)rne16(e);
      }
    }
    __builtin_amdgcn_wave_barrier();
    // ---- PV: out[32q][64d] += P[32q][64k] * V[64k][64d] ----
#pragma unroll
    for (int kst = 0; kst < 4; ++kst) {
      FragU ap;
      const ushort* pp = &plds[wid][l31][kst * 16 + lhi * 8];
      uint2 plo = *reinterpret_cast<const uint2*>(pp);
      uint2 phi = *reinterpret_cast<const uint2*>(pp + 4);
      ap.q = make_uint4(plo.x, plo.y, phi.x, phi.y);
      FragU bv0, bv1;
      const ushort* vp0 = vbase + (size_t)l31 * 1024 + k0 + kst * 16 + lhi * 8;
      bv0.q = *reinterpret_cast<const uint4*>(vp0);
      bv1.q = *reinterpret_cast<const uint4*>(vp0 + 32 * 1024);
      oacc0 = MFMA(ap.v, bv0.v, oacc0);
      oacc1 = MFMA(ap.v, bv1.v, oacc1);
    }
  }

  // ---- reduce den across the 32-lane half (q-rows match reg layout) ----
#pragma unroll
  for (int r = 0; r < 16; ++r) {
    float s = pden[r];
    s += __shfl_xor(s, 1);
    s += __shfl_xor(s, 2);
    s += __shfl_xor(s, 4);
    s += __shfl_xor(s, 8);
    s += __shfl_xor(s, 16);
    pden[r] = 1.0f / s;
  }

  // ---- write O bf16: row m = b*1024 + q, col = h*64 + d ----
  const int b = bh >> 4, h = bh & 15;
#pragma unroll
  for (int r = 0; r < 16; ++r) {
    int q = q0 + (r & 3) + ((r >> 2) << 3) + 4 * lhi;
    size_t row = ((size_t)b * 1024 + q) * 1024 + h * 64;
    O[row + l31] = (ushort)rne16(oacc0[r] * pden[r]);
    O[row + 32 + l31] = (ushort)rne16(oacc1[r] * pden[r]);
  }
}

// ---------------------------------------------------------------------------
// Final projection: Y[m][n] = sum_k obuf_bf16[m][k] * Wo[n][k]
// ---------------------------------------------------------------------------
__global__ __launch_bounds__(256) void k_final(const ushort* __restrict__ Xb,
                                               const float* __restrict__ W,
                                               float* __restrict__ Y) {
  __shared__ __align__(16) char smem[12288];

  const int m0 = blockIdx.y * 128;
  const int n0 = blockIdx.x * 64;
  const int tid = threadIdx.x;
  const int l = tid & 63;
  const int wid = tid >> 6;
  const int wr = wid >> 1, wc = wid & 1;
  const int l31 = l & 31, lhi = l >> 5;
  const int sr = tid >> 2;
  const int sc = tid & 3;

  f32x16 acc0 = 0.0f, acc1 = 0.0f;

  for (int k0 = 0; k0 < 1024; k0 += 32) {
    uint4 av[2];
    float4 b0, b1;
#pragma unroll
    for (int sl = 0; sl < 2; ++sl)
      av[sl] = *reinterpret_cast<const uint4*>(
          Xb + (size_t)(m0 + sr + 64 * sl) * 1024 + k0 + sc * 8);
    {
      const float* bp = W + (size_t)(n0 + sr) * 1024 + k0 + sc * 8;
      b0 = *reinterpret_cast<const float4*>(bp);
      b1 = *reinterpret_cast<const float4*>(bp + 4);
    }
    __syncthreads();
#pragma unroll
    for (int sl = 0; sl < 2; ++sl) {
      int row = sr + 64 * sl;
      int off = row * 64 + ((sc ^ ((row >> 1) & 3)) << 4);
      *reinterpret_cast<uint4*>(smem + off) = av[sl];
    }
    {
      int off = sr * 64 + ((sc ^ ((sr >> 1) & 3)) << 4);
      *reinterpret_cast<uint4*>(smem + 8192 + off) = rne8(b0, b1);
    }
    __syncthreads();

#pragma unroll
    for (int kst = 0; kst < 2; ++kst) {
      FragU ah[2], bh;
#pragma unroll
      for (int fm = 0; fm < 2; ++fm) {
        int row = wr * 64 + fm * 32 + l31;
        int cc = (kst * 2 + lhi) ^ ((row >> 1) & 3);
        ah[fm].q = *reinterpret_cast<const uint4*>(smem + row * 64 + cc * 16);
      }
      int brow = wc * 32 + l31;
      int bcc = (kst * 2 + lhi) ^ ((brow >> 1) & 3);
      bh.q = *reinterpret_cast<const uint4*>(smem + 8192 + brow * 64 + bcc * 16);
      acc0 = MFMA(ah[0].v, bh.v, acc0);
      acc1 = MFMA(ah[1].v, bh.v, acc1);
    }
  }

#pragma unroll
  for (int fm = 0; fm < 2; ++fm) {
    const f32x16& a = fm ? acc1 : acc0;
#pragma unroll
    for (int j = 0; j < 16; ++j) {
      int rl = fm * 32 + (j & 3) + ((j >> 2) & 3) * 8 + 4 * lhi;
      int m = m0 + wr * 64 + rl;
      Y[(size_t)m * 1024 + n0 + wc * 32 + l31] = a[j];
    }
  }
}

// ---------------------------------------------------------------------------
extern "C" void kernel_launch(void* const* d_in, const int* in_sizes, int n_in,
                              void* d_out, int out_size, void* d_ws,
                              size_t ws_size, hipStream_t stream) {
  const float* x = (const float*)d_in[0];
  const float* Wq = (const float*)d_in[1];
  const float* Wk = (const float*)d_in[2];
  const float* Wv = (const float*)d_in[3];
  const float* Wo = (const float*)d_in[4];
  const float* tpl = (const float*)d_in[5];
  const float* proj = (const float*)d_in[6];
  float* out = (float*)d_out;

  char* ws = (char*)d_ws;
  size_t off = 0;
  auto alloc = [&](size_t bytes) {
    void* p = ws + off;
    off += (bytes + 255) & ~(size_t)255;
    return p;
  };
  // ws: cs 256K + Ah 128K + qs 2M + ks 2M + vt 4M + obuf 4M  (~12.4 MB)
  float* cs = (float*)alloc((size_t)1024 * 64 * 4);
  ushort* Ahh = (ushort*)alloc((size_t)16 * 32 * 64 * 2);
  ushort* Ahl = (ushort*)alloc((size_t)16 * 32 * 64 * 2);
  ushort* qs = (ushort*)alloc((size_t)32 * 1024 * 32 * 2);
  ushort* ks = (ushort*)alloc((size_t)32 * 1024 * 32 * 2);
  ushort* vt = (ushort*)alloc((size_t)32 * 64 * 1024 * 2);
  ushort* obuf = (ushort*)alloc((size_t)2 * 1024 * 1024 * 2);

  k_cs<<<dim3(512), dim3(64), 0, stream>>>(cs);
  k_prep_A<<<dim3(512), dim3(64), 0, stream>>>(tpl, proj, Ahh, Ahl);
  k_qkv<<<dim3(16, 16, 3), dim3(256), 0, stream>>>(x, Wq, Wk, Wv, Ahh, Ahl, cs,
                                                   qs, ks, vt);
  k_attn<<<dim3(8, 32), dim3(256), 0, stream>>>(qs, ks, vt, obuf);
  k_final<<<dim3(16, 16), dim3(256), 0, stream>>>(obuf, Wo, out);
}

// Round 5
// 119.156 us; speedup vs baseline: 3.7389x; 1.2973x over previous
//
#include <hip/hip_runtime.h>
#include <math.h>

#define S_ 1024
#define T_ 32
#define SCALE_F 0.7071067811865476f

typedef unsigned int uint;
typedef unsigned short ushort;
typedef __bf16 bf16x8 __attribute__((ext_vector_type(8)));
typedef float f32x16 __attribute__((ext_vector_type(16)));

union FragU { uint4 q; bf16x8 v; };

#define MFMA(a, b, c) __builtin_amdgcn_mfma_f32_32x32x16_bf16((a), (b), (c), 0, 0, 0)

__device__ __forceinline__ uint rne16(float f) {
  uint u = __builtin_bit_cast(uint, f);
  u += 0x7fffu + ((u >> 16) & 1u);
  return u >> 16;
}

// exact truncation split: f = hi + rem, lo = trunc-bf16(rem)
__device__ __forceinline__ void split8(const float4& A, const float4& B,
                                       uint4& hi, uint4& lo) {
  float f[8] = {A.x, A.y, A.z, A.w, B.x, B.y, B.z, B.w};
  uint h[8], m[8];
#pragma unroll
  for (int i = 0; i < 8; ++i) {
    uint u = __builtin_bit_cast(uint, f[i]);
    h[i] = u >> 16;
    float fh = __builtin_bit_cast(float, u & 0xffff0000u);
    m[i] = __builtin_bit_cast(uint, f[i] - fh) >> 16;
  }
  hi = make_uint4(h[0] | (h[1] << 16), h[2] | (h[3] << 16),
                  h[4] | (h[5] << 16), h[6] | (h[7] << 16));
  lo = make_uint4(m[0] | (m[1] << 16), m[2] | (m[3] << 16),
                  m[4] | (m[5] << 16), m[6] | (m[7] << 16));
}

__device__ __forceinline__ void split8a(const float* f, uint4& hi, uint4& lo) {
  uint h[8], m[8];
#pragma unroll
  for (int i = 0; i < 8; ++i) {
    uint u = __builtin_bit_cast(uint, f[i]);
    h[i] = u >> 16;
    float fh = __builtin_bit_cast(float, u & 0xffff0000u);
    m[i] = __builtin_bit_cast(uint, f[i] - fh) >> 16;
  }
  hi = make_uint4(h[0] | (h[1] << 16), h[2] | (h[3] << 16),
                  h[4] | (h[5] << 16), h[6] | (h[7] << 16));
  lo = make_uint4(m[0] | (m[1] << 16), m[2] | (m[3] << 16),
                  m[4] | (m[5] << 16), m[6] | (m[7] << 16));
}

__device__ __forceinline__ uint4 rne8(const float4& A, const float4& B) {
  float f[8] = {A.x, A.y, A.z, A.w, B.x, B.y, B.z, B.w};
  uint h[8];
#pragma unroll
  for (int i = 0; i < 8; ++i) h[i] = rne16(f[i]);
  return make_uint4(h[0] | (h[1] << 16), h[2] | (h[3] << 16),
                    h[4] | (h[5] << 16), h[6] | (h[7] << 16));
}

// ---------------------------------------------------------------------------
// cos/sin table
// ---------------------------------------------------------------------------
__global__ __launch_bounds__(64) void k_cs(float* __restrict__ cs) {
  int s = blockIdx.x * 2 + (threadIdx.x >> 5);
  int p = threadIdx.x & 31;
  float invf = powf(10000.0f, (-2.0f * p) / 64.0f);
  float sn, c;
  sincosf((float)s * invf, &sn, &c);
  cs[s * 64 + 2 * p] = c;
  cs[s * 64 + 2 * p + 1] = sn;
}

// ---------------------------------------------------------------------------
// f32 -> bf16 (RNE) bulk convert (for Wo)
// ---------------------------------------------------------------------------
__global__ __launch_bounds__(256) void k_cvt(const float* __restrict__ W,
                                             ushort* __restrict__ Wb) {
  int i = (blockIdx.x * 256 + threadIdx.x) * 8;
  float4 a = *reinterpret_cast<const float4*>(W + i);
  float4 b = *reinterpret_cast<const float4*>(W + i + 4);
  *reinterpret_cast<uint4*>(Wb + i) = rne8(a, b);
}

// ---------------------------------------------------------------------------
// A[h,t,i] = (1/8) * sum_j proj[h,j] * tpl_norm[h,t,(i-j) mod 64]  -> hi/lo bf16
// ---------------------------------------------------------------------------
__global__ __launch_bounds__(64) void k_prep_A(const float* __restrict__ tpl,
                                               const float* __restrict__ proj,
                                               ushort* __restrict__ Ahh,
                                               ushort* __restrict__ Ahl) {
  int ht = blockIdx.x;  // h*32 + t
  int h = ht >> 5;
  int lane = threadIdx.x;
  float tv = tpl[ht * 64 + lane];
  float ss = tv * tv;
#pragma unroll
  for (int off = 1; off < 64; off <<= 1) ss += __shfl_xor(ss, off);
  float rn = 1.0f / fmaxf(sqrtf(ss), 1e-12f);
  __shared__ float tn[64];
  tn[lane] = tv * rn;
  __syncthreads();
  float acc = 0.f;
#pragma unroll
  for (int j = 0; j < 64; ++j) acc += proj[h * 64 + j] * tn[(lane - j) & 63];
  float v = acc * 0.125f;
  uint u = __builtin_bit_cast(uint, v);
  uint hi = u >> 16;
  float fh = __builtin_bit_cast(float, u & 0xffff0000u);
  uint lo = __builtin_bit_cast(uint, v - fh) >> 16;
  Ahh[ht * 64 + lane] = (ushort)hi;
  Ahl[ht * 64 + lane] = (ushort)lo;
}

// ---------------------------------------------------------------------------
// Fused QKV MFMA GEMM (unchanged, validated round-4).
// z<2: hi/lo 3-product + RoPE/signature epilogue -> Sig stored bf16.
// z==2: single product -> V stored TRANSPOSED bf16: Vt[b][h][d][s].
// ---------------------------------------------------------------------------
__global__ __launch_bounds__(256) void k_qkv(
    const float* __restrict__ X,
    const float* __restrict__ Wq, const float* __restrict__ Wk,
    const float* __restrict__ Wv,
    const ushort* __restrict__ Ahh, const ushort* __restrict__ Ahl,
    const float* __restrict__ cs,
    ushort* __restrict__ Qs, ushort* __restrict__ Ks,
    ushort* __restrict__ Vt) {
  __shared__ __align__(16) char smem[34816];

  const int z = blockIdx.z;
  const float* Wm = (z == 0) ? Wq : (z == 1) ? Wk : Wv;
  const int m0 = blockIdx.y * 128;
  const int n0 = blockIdx.x * 64;
  const int h = blockIdx.x;

  const int tid = threadIdx.x;
  const int l = tid & 63;
  const int wid = tid >> 6;
  const int wr = wid >> 1, wc = wid & 1;
  const int l31 = l & 31, lhi = l >> 5;

  const int sr = tid >> 2;
  const int sc = tid & 3;

  f32x16 acc0 = 0.0f, acc1 = 0.0f;

  for (int k0 = 0; k0 < 1024; k0 += 32) {
    float4 a0[2], a1[2], b0, b1;
#pragma unroll
    for (int sl = 0; sl < 2; ++sl) {
      const float* ap = X + (size_t)(m0 + sr + 64 * sl) * 1024 + k0 + sc * 8;
      a0[sl] = *reinterpret_cast<const float4*>(ap);
      a1[sl] = *reinterpret_cast<const float4*>(ap + 4);
    }
    {
      const float* bp = Wm + (size_t)(n0 + sr) * 1024 + k0 + sc * 8;
      b0 = *reinterpret_cast<const float4*>(bp);
      b1 = *reinterpret_cast<const float4*>(bp + 4);
    }
    __syncthreads();
    if (z < 2) {
#pragma unroll
      for (int sl = 0; sl < 2; ++sl) {
        uint4 hi, lo;
        split8(a0[sl], a1[sl], hi, lo);
        int row = sr + 64 * sl;
        int off = row * 64 + ((sc ^ ((row >> 1) & 3)) << 4);
        *reinterpret_cast<uint4*>(smem + off) = hi;
        *reinterpret_cast<uint4*>(smem + 8192 + off) = lo;
      }
      {
        uint4 hi, lo;
        split8(b0, b1, hi, lo);
        int off = sr * 64 + ((sc ^ ((sr >> 1) & 3)) << 4);
        *reinterpret_cast<uint4*>(smem + 16384 + off) = hi;
        *reinterpret_cast<uint4*>(smem + 20480 + off) = lo;
      }
    } else {
#pragma unroll
      for (int sl = 0; sl < 2; ++sl) {
        int row = sr + 64 * sl;
        int off = row * 64 + ((sc ^ ((row >> 1) & 3)) << 4);
        *reinterpret_cast<uint4*>(smem + off) = rne8(a0[sl], a1[sl]);
      }
      int off = sr * 64 + ((sc ^ ((sr >> 1) & 3)) << 4);
      *reinterpret_cast<uint4*>(smem + 16384 + off) = rne8(b0, b1);
    }
    __syncthreads();

#pragma unroll
    for (int kst = 0; kst < 2; ++kst) {
      FragU ah[2], al[2], bh, bl;
#pragma unroll
      for (int fm = 0; fm < 2; ++fm) {
        int row = wr * 64 + fm * 32 + l31;
        int cc = (kst * 2 + lhi) ^ ((row >> 1) & 3);
        ah[fm].q = *reinterpret_cast<const uint4*>(smem + row * 64 + cc * 16);
        if (z < 2)
          al[fm].q =
              *reinterpret_cast<const uint4*>(smem + 8192 + row * 64 + cc * 16);
      }
      {
        int brow = wc * 32 + l31;
        int bcc = (kst * 2 + lhi) ^ ((brow >> 1) & 3);
        bh.q =
            *reinterpret_cast<const uint4*>(smem + 16384 + brow * 64 + bcc * 16);
        if (z < 2)
          bl.q = *reinterpret_cast<const uint4*>(smem + 20480 + brow * 64 +
                                                 bcc * 16);
      }
      if (z < 2) {
        acc0 = MFMA(al[0].v, bh.v, acc0);
        acc0 = MFMA(ah[0].v, bl.v, acc0);
        acc1 = MFMA(al[1].v, bh.v, acc1);
        acc1 = MFMA(ah[1].v, bl.v, acc1);
      }
      acc0 = MFMA(ah[0].v, bh.v, acc0);
      acc1 = MFMA(ah[1].v, bh.v, acc1);
    }
  }

  if (z == 2) {
    int d = wc * 32 + l31;
#pragma unroll
    for (int fm = 0; fm < 2; ++fm) {
      const f32x16& a = fm ? acc1 : acc0;
#pragma unroll
      for (int j = 0; j < 16; ++j) {
        int rl = fm * 32 + (j & 3) + ((j >> 2) & 3) * 8 + 4 * lhi;
        int m = m0 + wr * 64 + rl;
        int b = m >> 10, s = m & 1023;
        Vt[((size_t)((b * 16 + h) * 64 + d)) * 1024 + s] = (ushort)rne16(a[j]);
      }
    }
    return;
  }

  ushort* Sig = (z == 0) ? Qs : Ks;
  float* dmp = reinterpret_cast<float*>(smem);  // [2][64][68]
  __syncthreads();
#pragma unroll
  for (int fm = 0; fm < 2; ++fm) {
    const f32x16& a = fm ? acc1 : acc0;
#pragma unroll
    for (int j = 0; j < 16; ++j) {
      int rl = fm * 32 + (j & 3) + ((j >> 2) & 3) * 8 + 4 * lhi;
      dmp[(wr * 64 + rl) * 68 + wc * 32 + l31] = a[j];
    }
  }
  __syncthreads();

  int srow = wr * 64 + wc * 32 + l31;
  int sq = (m0 + srow) & 1023;
  f32x16 sacc = 0.0f;
#pragma unroll
  for (int kst = 0; kst < 4; ++kst) {
    const float* dp = &dmp[srow * 68 + kst * 16 + lhi * 8];
    float4 x0 = *reinterpret_cast<const float4*>(dp);
    float4 x1 = *reinterpret_cast<const float4*>(dp + 4);
    const float* cp = &cs[sq * 64 + kst * 16 + lhi * 8];
    float4 c0 = *reinterpret_cast<const float4*>(cp);
    float4 c1 = *reinterpret_cast<const float4*>(cp + 4);
    float r[8];
    r[0] = x0.x * c0.x - x0.y * c0.y;
    r[1] = x0.x * c0.y + x0.y * c0.x;
    r[2] = x0.z * c0.z - x0.w * c0.w;
    r[3] = x0.z * c0.w + x0.w * c0.z;
    r[4] = x1.x * c1.x - x1.y * c1.y;
    r[5] = x1.x * c1.y + x1.y * c1.x;
    r[6] = x1.z * c1.z - x1.w * c1.w;
    r[7] = x1.z * c1.w + x1.w * c1.z;
    FragU ah, al;
    split8a(r, ah.q, al.q);
    size_t boff = ((size_t)(h * 32 + l31) * 64 + kst * 16 + lhi * 8);
    FragU bh, bl;
    bh.q = *reinterpret_cast<const uint4*>(Ahh + boff);
    bl.q = *reinterpret_cast<const uint4*>(Ahl + boff);
    sacc = MFMA(al.v, bh.v, sacc);
    sacc = MFMA(ah.v, bl.v, sacc);
    sacc = MFMA(ah.v, bh.v, sacc);
  }
#pragma unroll
  for (int j = 0; j < 16; ++j) {
    float v = sacc[j];
    float ss = v * v;
    ss += __shfl_xor(ss, 1);
    ss += __shfl_xor(ss, 2);
    ss += __shfl_xor(ss, 4);
    ss += __shfl_xor(ss, 8);
    ss += __shfl_xor(ss, 16);
    float rn = 1.0f / fmaxf(sqrtf(ss), 1e-12f);
    int rl = (j & 3) + ((j >> 2) & 3) * 8 + 4 * lhi;
    int m = m0 + wr * 64 + wc * 32 + rl;
    int bb = m >> 10, s2 = m & 1023;
    Sig[(((size_t)(bb * 16 + h)) * 1024 + s2) * 32 + l31] =
        (ushort)rne16(v * rn);
  }
}

// ---------------------------------------------------------------------------
// MFMA attention (validated structure; now 2-wave blocks for 2x blocks/CU).
// ---------------------------------------------------------------------------
__global__ __launch_bounds__(128) void k_attn(const ushort* __restrict__ Qs,
                                              const ushort* __restrict__ Ks,
                                              const ushort* __restrict__ Vt,
                                              ushort* __restrict__ O) {
  __shared__ ushort plds[2][32][68];

  const int tid = threadIdx.x;
  const int l = tid & 63;
  const int wid = tid >> 6;
  const int l31 = l & 31, lhi = l >> 5;
  const int bh = blockIdx.y;
  const int q0 = blockIdx.x * 64 + wid * 32;

  FragU aq0, aq1;
  {
    const ushort* qp = Qs + ((size_t)bh * 1024 + q0 + l31) * 32 + lhi * 8;
    aq0.q = *reinterpret_cast<const uint4*>(qp);
    aq1.q = *reinterpret_cast<const uint4*>(qp + 16);
  }

  const ushort* kbase = Ks + (size_t)bh * 1024 * 32;
  const ushort* vbase = Vt + (size_t)bh * 64 * 1024;

  f32x16 oacc0 = 0.0f, oacc1 = 0.0f;
  float pden[16];
#pragma unroll
  for (int r = 0; r < 16; ++r) pden[r] = 0.f;

  for (int kt = 0; kt < 16; ++kt) {
    const int k0 = kt * 64;
    f32x16 sacc[2];
    sacc[0] = 0.0f;
    sacc[1] = 0.0f;
#pragma unroll
    for (int nt = 0; nt < 2; ++nt) {
      const ushort* kp = kbase + (size_t)(k0 + nt * 32 + l31) * 32 + lhi * 8;
      FragU b0, b1;
      b0.q = *reinterpret_cast<const uint4*>(kp);
      b1.q = *reinterpret_cast<const uint4*>(kp + 16);
      sacc[nt] = MFMA(aq0.v, b0.v, sacc[nt]);
      sacc[nt] = MFMA(aq1.v, b1.v, sacc[nt]);
    }
#pragma unroll
    for (int nt = 0; nt < 2; ++nt) {
#pragma unroll
      for (int r = 0; r < 16; ++r) {
        float e = __expf(sacc[nt][r] * SCALE_F);
        pden[r] += e;
        int q = (r & 3) + ((r >> 2) << 3) + 4 * lhi;
        plds[wid][q][nt * 32 + l31] = (ushort)rne16(e);
      }
    }
    __builtin_amdgcn_wave_barrier();
#pragma unroll
    for (int kst = 0; kst < 4; ++kst) {
      FragU ap;
      const ushort* pp = &plds[wid][l31][kst * 16 + lhi * 8];
      uint2 plo = *reinterpret_cast<const uint2*>(pp);
      uint2 phi = *reinterpret_cast<const uint2*>(pp + 4);
      ap.q = make_uint4(plo.x, plo.y, phi.x, phi.y);
      FragU bv0, bv1;
      const ushort* vp0 = vbase + (size_t)l31 * 1024 + k0 + kst * 16 + lhi * 8;
      bv0.q = *reinterpret_cast<const uint4*>(vp0);
      bv1.q = *reinterpret_cast<const uint4*>(vp0 + 32 * 1024);
      oacc0 = MFMA(ap.v, bv0.v, oacc0);
      oacc1 = MFMA(ap.v, bv1.v, oacc1);
    }
  }

#pragma unroll
  for (int r = 0; r < 16; ++r) {
    float s = pden[r];
    s += __shfl_xor(s, 1);
    s += __shfl_xor(s, 2);
    s += __shfl_xor(s, 4);
    s += __shfl_xor(s, 8);
    s += __shfl_xor(s, 16);
    pden[r] = 1.0f / s;
  }

  const int b = bh >> 4, h = bh & 15;
#pragma unroll
  for (int r = 0; r < 16; ++r) {
    int q = q0 + (r & 3) + ((r >> 2) << 3) + 4 * lhi;
    size_t row = ((size_t)b * 1024 + q) * 1024 + h * 64;
    O[row + l31] = (ushort)rne16(oacc0[r] * pden[r]);
    O[row + 32 + l31] = (ushort)rne16(oacc1[r] * pden[r]);
  }
}

// ---------------------------------------------------------------------------
// Final projection: 64x64 tile, all-bf16 staging, grid (16,32) = 512 blocks
// (2 blocks/CU; the old 128x64 grid was 1 block/CU -> latency-bound at 69 TF).
// ---------------------------------------------------------------------------
__global__ __launch_bounds__(256) void k_final(const ushort* __restrict__ Xb,
                                               const ushort* __restrict__ Wb,
                                               float* __restrict__ Y) {
  __shared__ __align__(16) char smem[8192];  // A 4KB + B 4KB

  const int m0 = blockIdx.y * 64;
  const int n0 = blockIdx.x * 64;
  const int tid = threadIdx.x;
  const int l = tid & 63;
  const int wid = tid >> 6;
  const int wr = wid >> 1, wc = wid & 1;
  const int l31 = l & 31, lhi = l >> 5;
  const int sr = tid >> 2;
  const int sc = tid & 3;

  f32x16 acc = 0.0f;

  for (int k0 = 0; k0 < 1024; k0 += 32) {
    uint4 av = *reinterpret_cast<const uint4*>(
        Xb + (size_t)(m0 + sr) * 1024 + k0 + sc * 8);
    uint4 bv = *reinterpret_cast<const uint4*>(
        Wb + (size_t)(n0 + sr) * 1024 + k0 + sc * 8);
    __syncthreads();
    int off = sr * 64 + ((sc ^ ((sr >> 1) & 3)) << 4);
    *reinterpret_cast<uint4*>(smem + off) = av;
    *reinterpret_cast<uint4*>(smem + 4096 + off) = bv;
    __syncthreads();

#pragma unroll
    for (int kst = 0; kst < 2; ++kst) {
      FragU ah, bh;
      int row = wr * 32 + l31;
      int cc = (kst * 2 + lhi) ^ ((row >> 1) & 3);
      ah.q = *reinterpret_cast<const uint4*>(smem + row * 64 + cc * 16);
      int brow = wc * 32 + l31;
      int bcc = (kst * 2 + lhi) ^ ((brow >> 1) & 3);
      bh.q = *reinterpret_cast<const uint4*>(smem + 4096 + brow * 64 + bcc * 16);
      acc = MFMA(ah.v, bh.v, acc);
    }
  }

#pragma unroll
  for (int j = 0; j < 16; ++j) {
    int rl = (j & 3) + ((j >> 2) & 3) * 8 + 4 * lhi;
    int m = m0 + wr * 32 + rl;
    Y[(size_t)m * 1024 + n0 + wc * 32 + l31] = acc[j];
  }
}

// ---------------------------------------------------------------------------
extern "C" void kernel_launch(void* const* d_in, const int* in_sizes, int n_in,
                              void* d_out, int out_size, void* d_ws,
                              size_t ws_size, hipStream_t stream) {
  const float* x = (const float*)d_in[0];
  const float* Wq = (const float*)d_in[1];
  const float* Wk = (const float*)d_in[2];
  const float* Wv = (const float*)d_in[3];
  const float* Wo = (const float*)d_in[4];
  const float* tpl = (const float*)d_in[5];
  const float* proj = (const float*)d_in[6];
  float* out = (float*)d_out;

  char* ws = (char*)d_ws;
  size_t off = 0;
  auto alloc = [&](size_t bytes) {
    void* p = ws + off;
    off += (bytes + 255) & ~(size_t)255;
    return p;
  };
  // ws: cs 256K + Ah 128K + qs 2M + ks 2M + vt 4M + obuf 4M + Wob 2M  (~14.4MB)
  float* cs = (float*)alloc((size_t)1024 * 64 * 4);
  ushort* Ahh = (ushort*)alloc((size_t)16 * 32 * 64 * 2);
  ushort* Ahl = (ushort*)alloc((size_t)16 * 32 * 64 * 2);
  ushort* qs = (ushort*)alloc((size_t)32 * 1024 * 32 * 2);
  ushort* ks = (ushort*)alloc((size_t)32 * 1024 * 32 * 2);
  ushort* vt = (ushort*)alloc((size_t)32 * 64 * 1024 * 2);
  ushort* obuf = (ushort*)alloc((size_t)2 * 1024 * 1024 * 2);
  ushort* Wob = (ushort*)alloc((size_t)1024 * 1024 * 2);

  k_cs<<<dim3(512), dim3(64), 0, stream>>>(cs);
  k_prep_A<<<dim3(512), dim3(64), 0, stream>>>(tpl, proj, Ahh, Ahl);
  k_cvt<<<dim3(512), dim3(256), 0, stream>>>(Wo, Wob);
  k_qkv<<<dim3(16, 16, 3), dim3(256), 0, stream>>>(x, Wq, Wk, Wv, Ahh, Ahl, cs,
                                                   qs, ks, vt);
  k_attn<<<dim3(16, 32), dim3(128), 0, stream>>>(qs, ks, vt, obuf);
  k_final<<<dim3(16, 32), dim3(256), 0, stream>>>(obuf, Wob, out);
}